// Round 18
// baseline (611.959 us; speedup 1.0000x reference)
//
#include <hip/hip_runtime.h>

// Problem constants
#define NB   64
#define LA   256
#define DD   512
#define NCLS 10
#define NREF 50
#define NNEG 100
#define MARGIN 10.0f
#define NITER 27

#define LOG2E 1.44269504f
#define LN2   0.69314718f
#define LC50  (-3.9120230054f)   // log(1/50)
#define LC100 (-4.6051701860f)   // log(1/100)

// ---- workspace layout (float offsets) ----
// cross cost stored TRANSPOSED: [b][500][256] (t0-point major)
#define OFF_CX   ((size_t)0)
#define SZ_CX    ((size_t)64*500*256)
#define OFF_CAA  (OFF_CX + SZ_CX)
#define SZ_CAA   ((size_t)64*256*256)
#define OFF_CNN  (OFF_CAA + SZ_CAA)
#define SZ_CNN   ((size_t)64*100*100)
#define OFF_CLN  (OFF_CNN + SZ_CNN)
#define SZ_CLN   ((size_t)64*50*100)
#define OFF_CGN  (OFF_CLN + SZ_CLN)
#define SZ_CGN   ((size_t)64*50*100)
#define OFF_CTT  (OFF_CGN + SZ_CGN)
#define SZ_CTT   ((size_t)10*50*50)
#define OFF_SQA  (OFF_CTT + SZ_CTT)
#define OFF_SQN  (OFF_SQA + (size_t)64*256)
#define OFF_SQT  (OFF_SQN + (size_t)64*100)
#define OFF_OTX  (OFF_SQT + (size_t)500)
#define OFF_OTAA (OFF_OTX + (size_t)640)
#define OFF_OTNN (OFF_OTAA + (size_t)64)
#define OFF_OTLN (OFF_OTNN + (size_t)64)
#define OFF_OTGN (OFF_OTLN + (size_t)64)
#define OFF_OTTT (OFF_OTGN + (size_t)64)

__device__ __forceinline__ float eps_at(int it) {
    return (it < 12) ? ldexpf(8.0f, -it) : 0.0025f;
}

// ---------------- K0: 0.5 * squared norms ----------------
__global__ __launch_bounds__(256) void sq_kernel(const float* __restrict__ anchor,
                                                 const float* __restrict__ neg,
                                                 const float* __restrict__ t0,
                                                 float* __restrict__ ws) {
    int gw   = (blockIdx.x * 256 + threadIdx.x) >> 6;
    int lane = threadIdx.x & 63;
    const int nA = NB * LA, nN = NB * NNEG, nT = NCLS * NREF;
    if (gw >= nA + nN + nT) return;
    const float* row; float* outp;
    if (gw < nA)           { row = anchor + (size_t)gw * DD;          outp = ws + OFF_SQA + gw; }
    else if (gw < nA + nN) { int r = gw - nA;      row = neg + (size_t)r * DD; outp = ws + OFF_SQN + r; }
    else                   { int r = gw - nA - nN; row = t0  + (size_t)r * DD; outp = ws + OFF_SQT + r; }
    const float4* r4 = (const float4*)row;
    float4 u = r4[lane * 2], v = r4[lane * 2 + 1];
    float s = u.x*u.x + u.y*u.y + u.z*u.z + u.w*u.w
            + v.x*v.x + v.y*v.y + v.z*v.z + v.w*v.w;
    #pragma unroll
    for (int off = 1; off < 64; off <<= 1) s += __shfl_xor(s, off);
    if (lane == 0) *outp = 0.5f * s;
}

// ---------------- K1: cost matrices — 128x128 tile, 8x8 micro, K=16 ----------------
#define CTM 128
#define CTK 16
__global__ __launch_bounds__(256) void cost128(const float* __restrict__ anchor,
                                               const float* __restrict__ neg,
                                               const float* __restrict__ t0,
                                               const int* __restrict__ gneg,
                                               float* __restrict__ ws) {
    __shared__ __align__(16) float As[CTK][CTM];
    __shared__ __align__(16) float Bs[CTK][CTM];
    int bid = blockIdx.x, tid = threadIdx.x;
    const float *X, *Y, *sqx, *sqy;
    float* Cout; int N, M, ldc, r0, c0;
    bool tr = false;
    if (bid < 512) {
        int b = bid >> 3, t = bid & 7;
        r0 = (t >> 2) * 128; c0 = (t & 3) * 128;
        X = anchor + (size_t)b * LA * DD; Y = t0; N = LA; M = 500; ldc = 500;
        Cout = ws + OFF_CX + (size_t)b * 500 * 256;
        sqx = ws + OFF_SQA + b * LA; sqy = ws + OFF_SQT;
        tr = true;
    } else if (bid < 768) {
        int b2 = bid - 512; int b = b2 >> 2, t = b2 & 3;
        r0 = (t >> 1) * 128; c0 = (t & 1) * 128;
        X = Y = anchor + (size_t)b * LA * DD; N = M = LA; ldc = LA;
        Cout = ws + OFF_CAA + (size_t)b * LA * LA;
        sqx = sqy = ws + OFF_SQA + b * LA;
    } else if (bid < 832) {
        int b = bid - 768; r0 = 0; c0 = 0;
        X = Y = neg + (size_t)b * NNEG * DD; N = M = NNEG; ldc = NNEG;
        Cout = ws + OFF_CNN + (size_t)b * NNEG * NNEG;
        sqx = sqy = ws + OFF_SQN + b * NNEG;
    } else if (bid < 896) {
        int b = bid - 832; r0 = 0; c0 = 0;
        X = t0 + (size_t)9 * NREF * DD; Y = neg + (size_t)b * NNEG * DD;
        N = NREF; M = NNEG; ldc = NNEG;
        Cout = ws + OFF_CLN + (size_t)b * NREF * NNEG;
        sqx = ws + OFF_SQT + 9 * NREF; sqy = ws + OFF_SQN + b * NNEG;
    } else if (bid < 960) {
        int b = bid - 896; r0 = 0; c0 = 0;
        int gc = gneg[b];
        X = t0 + (size_t)gc * NREF * DD; Y = neg + (size_t)b * NNEG * DD;
        N = NREF; M = NNEG; ldc = NNEG;
        Cout = ws + OFF_CGN + (size_t)b * NREF * NNEG;
        sqx = ws + OFF_SQT + gc * NREF; sqy = ws + OFF_SQN + b * NNEG;
    } else {
        int c = bid - 960; r0 = 0; c0 = 0;
        X = Y = t0 + (size_t)c * NREF * DD; N = M = NREF; ldc = NREF;
        Cout = ws + OFF_CTT + (size_t)c * NREF * NREF;
        sqx = sqy = ws + OFF_SQT + c * NREF;
    }
    int row = tid & 127, kq = tid >> 7;
    int tx = tid & 15, ty = tid >> 4;
    bool xok = (r0 + row) < N, yok = (c0 + row) < M;
    const float* xrow = X + (size_t)(r0 + row) * DD + kq * 8;
    const float* yrow = Y + (size_t)(c0 + row) * DD + kq * 8;
    float acc[8][8];
    #pragma unroll
    for (int a = 0; a < 8; a++)
        #pragma unroll
        for (int b = 0; b < 8; b++) acc[a][b] = 0.f;
    for (int k0 = 0; k0 < DD; k0 += CTK) {
        float4 xa0 = xok ? *(const float4*)(xrow + k0)     : make_float4(0,0,0,0);
        float4 xa1 = xok ? *(const float4*)(xrow + k0 + 4) : make_float4(0,0,0,0);
        float4 ya0 = yok ? *(const float4*)(yrow + k0)     : make_float4(0,0,0,0);
        float4 ya1 = yok ? *(const float4*)(yrow + k0 + 4) : make_float4(0,0,0,0);
        __syncthreads();
        int kb = kq * 8;
        As[kb+0][row]=xa0.x; As[kb+1][row]=xa0.y; As[kb+2][row]=xa0.z; As[kb+3][row]=xa0.w;
        As[kb+4][row]=xa1.x; As[kb+5][row]=xa1.y; As[kb+6][row]=xa1.z; As[kb+7][row]=xa1.w;
        Bs[kb+0][row]=ya0.x; Bs[kb+1][row]=ya0.y; Bs[kb+2][row]=ya0.z; Bs[kb+3][row]=ya0.w;
        Bs[kb+4][row]=ya1.x; Bs[kb+5][row]=ya1.y; Bs[kb+6][row]=ya1.z; Bs[kb+7][row]=ya1.w;
        __syncthreads();
        #pragma unroll
        for (int k = 0; k < CTK; k++) {
            float4 a0 = *(const float4*)&As[k][ty << 3];
            float4 a1 = *(const float4*)&As[k][(ty << 3) + 4];
            float4 b0 = *(const float4*)&Bs[k][tx << 3];
            float4 b1 = *(const float4*)&Bs[k][(tx << 3) + 4];
            float av[8] = {a0.x,a0.y,a0.z,a0.w,a1.x,a1.y,a1.z,a1.w};
            float bv[8] = {b0.x,b0.y,b0.z,b0.w,b1.x,b1.y,b1.z,b1.w};
            #pragma unroll
            for (int a = 0; a < 8; a++)
                #pragma unroll
                for (int b = 0; b < 8; b++)
                    acc[a][b] = fmaf(av[a], bv[b], acc[a][b]);
        }
    }
    #pragma unroll
    for (int a = 0; a < 8; a++) {
        int n = r0 + (ty << 3) + a;
        if (n < N) {
            float sx = sqx[n];
            #pragma unroll
            for (int b = 0; b < 8; b++) {
                int m = c0 + (tx << 3) + b;
                if (m < M) {
                    float v = sx + sqy[m] - acc[a][b];
                    if (tr) Cout[(size_t)m * 256 + n] = v;
                    else    Cout[(size_t)n * ldc + m] = v;
                }
            }
        }
    }
}

// ---------------- K2: ALL sinkhorn in one launch (shfl-broadcast for uniform reads) ----------------
// 435 blocks x 1024 thr. bid<64 aa; 64..79 nn x4; 80..111 ln/gn x4; 112..114 tt x4;
// 115..434 cross x2 (512 thr each, 256 active).
__global__ __launch_bounds__(1024) void sink_fused(const float* __restrict__ weight,
                                                   float* __restrict__ ws) {
    __shared__ __align__(16) float smem[26664];
    int bid = blockIdx.x, tid = threadIdx.x;

    if (bid < 64) {
        // ---- aa: wave-uniform ahS slice loaded ONCE per app (1 ds_read), elements
        //      broadcast via __shfl (v_readlane, no DS traffic). pm/ps stride 260. ----
        float* ahS = smem;             // [256]
        float* pm  = smem + 256;       // [4][260]
        float* ps  = smem + 1296;      // [4][260]
        float* red = smem + 2336;      // [16]
        int w = tid >> 6, lane = tid & 63;
        int q = w >> 2;                          // row quarter 0..3
        int c = ((w & 3) << 6) | lane;           // column 0..255
        const float* Cg = ws + OFF_CAA + ((size_t)bid << 16);
        float Creg[64];
        #pragma unroll
        for (int k = 0; k < 64; ++k)
            Creg[k] = Cg[(size_t)((q << 6) + k) * 256 + c];
        float wgt = weight[(size_t)bid * LA + c];
        float la = (wgt > 0.f) ? __logf(fmaxf(wgt, 1e-30f)) : -1e9f;
        float h = 0.f, fs = 0.f;
        if (q == 0) ahS[c] = 8.0f * la;
        __syncthreads();
        int rbase = q << 6;
        for (int app = 0; app < 54; ++app) {
            float eps = eps_at(app >> 1);
            float ahv = ahS[rbase + lane];   // whole 64-slice across the wave's lanes
            float m0 = -3.4e38f, m1 = -3.4e38f, m2 = -3.4e38f, m3 = -3.4e38f;
            #pragma unroll
            for (int k = 0; k < 64; k += 4) {
                m0 = fmaxf(m0, __shfl(ahv, k + 0) - Creg[k + 0]);
                m1 = fmaxf(m1, __shfl(ahv, k + 1) - Creg[k + 1]);
                m2 = fmaxf(m2, __shfl(ahv, k + 2) - Creg[k + 2]);
                m3 = fmaxf(m3, __shfl(ahv, k + 3) - Creg[k + 3]);
            }
            pm[q * 260 + c] = fmaxf(fmaxf(m0, m1), fmaxf(m2, m3));
            __syncthreads();
            float m = fmaxf(fmaxf(pm[c], pm[260 + c]), fmaxf(pm[520 + c], pm[780 + c]));
            float ie2 = (1.0f / eps) * LOG2E;
            float s0 = 0.f, s1 = 0.f, s2 = 0.f, s3 = 0.f;
            #pragma unroll
            for (int k = 0; k < 64; k += 4) {
                s0 += exp2f((__shfl(ahv, k + 0) - Creg[k + 0] - m) * ie2);
                s1 += exp2f((__shfl(ahv, k + 1) - Creg[k + 1] - m) * ie2);
                s2 += exp2f((__shfl(ahv, k + 2) - Creg[k + 2] - m) * ie2);
                s3 += exp2f((__shfl(ahv, k + 3) - Creg[k + 3] - m) * ie2);
            }
            ps[q * 260 + c] = (s0 + s1) + (s2 + s3);
            __syncthreads();
            float s = (ps[c] + ps[260 + c]) + (ps[520 + c] + ps[780 + c]);
            h = -fmaf(eps * LN2, __log2f(s), m);
            if (app == 52) fs = h;
            if (q == 0) {
                float epsn = eps_at((app + 1) >> 1);
                ahS[c] = fmaf(epsn, la, h);
            }
            __syncthreads();
        }
        float contrib = (q == 0) ? wgt * (fs + h) : 0.f;
        #pragma unroll
        for (int off = 1; off < 64; off <<= 1) contrib += __shfl_xor(contrib, off);
        if (lane == 0) red[w] = contrib;
        __syncthreads();
        if (tid == 0) {
            float s = 0.f;
            #pragma unroll
            for (int k = 0; k < 16; ++k) s += red[k];
            ws[OFF_OTAA + bid] = s;
        }

    } else if (bid < 80) {
        // ---- nn x4 (100x100 sym): lane-paired, Creg[52], 1 barrier/app ----
        int sub = tid >> 8, stid = tid & 255;
        int inst = ((bid - 64) << 2) | sub;
        const float* Cg = ws + OFF_CNN + (size_t)inst * 10000;
        float* S = smem + (sub << 8);
        bool act = stid < 200;
        int c = stid >> 1, rg = stid & 1;
        float Creg[52];
        if (act) {
            #pragma unroll
            for (int k = 0; k < 52; ++k) {
                int r = rg * 52 + k;
                Creg[k] = (r < 100) ? Cg[(size_t)r * 100 + c] : 3.0e30f;
            }
        }
        if (stid < 100) S[stid] = 8.0f * LC100;
        if (stid >= 100 && stid < 104) { S[stid] = -1.0e30f; S[104 + stid] = -1.0e30f; }
        __syncthreads();
        float h = 0.f, fs = 0.f;
        for (int app = 0; app < 54; ++app) {
            float eps = eps_at(app >> 1);
            if (act) {
                const float4* a4 = (const float4*)(S + (app & 1) * 104 + rg * 52);
                float m0=-3.4e38f, m1=-3.4e38f, m2=-3.4e38f, m3=-3.4e38f;
                #pragma unroll
                for (int k = 0; k < 13; ++k) {
                    float4 av = a4[k];
                    m0 = fmaxf(m0, av.x - Creg[4*k+0]);
                    m1 = fmaxf(m1, av.y - Creg[4*k+1]);
                    m2 = fmaxf(m2, av.z - Creg[4*k+2]);
                    m3 = fmaxf(m3, av.w - Creg[4*k+3]);
                }
                float m = fmaxf(fmaxf(m0, m1), fmaxf(m2, m3));
                m = fmaxf(m, __shfl_xor(m, 1));
                float ie2 = (1.0f / eps) * LOG2E;
                float s0=0.f, s1=0.f, s2=0.f, s3=0.f;
                #pragma unroll
                for (int k = 0; k < 13; ++k) {
                    float4 av = a4[k];
                    s0 += exp2f((av.x - Creg[4*k+0] - m) * ie2);
                    s1 += exp2f((av.y - Creg[4*k+1] - m) * ie2);
                    s2 += exp2f((av.z - Creg[4*k+2] - m) * ie2);
                    s3 += exp2f((av.w - Creg[4*k+3] - m) * ie2);
                }
                float s = (s0 + s1) + (s2 + s3);
                s += __shfl_xor(s, 1);
                h = -fmaf(eps * LN2, __log2f(s), m);
                if (app == 52) fs = h;
                float epsn = eps_at((app + 1) >> 1);
                if (rg == 0) S[((app + 1) & 1) * 104 + c] = fmaf(epsn, LC100, h);
            }
            __syncthreads();
        }
        float contrib = (act && rg == 0) ? 0.01f * (fs + h) : 0.f;
        #pragma unroll
        for (int off = 1; off < 64; off <<= 1) contrib += __shfl_xor(contrib, off);
        if ((tid & 63) == 0) smem[1024 + (tid >> 6)] = contrib;
        __syncthreads();
        if (stid == 0) {
            int b4 = 1024 + (sub << 2);
            ws[OFF_OTNN + inst] = smem[b4] + smem[b4+1] + smem[b4+2] + smem[b4+3];
        }

    } else if (bid < 112) {
        // ---- ln/gn x4 (50x100): f lane-paired, g thread-per-col ----
        int sub = tid >> 8, stid = tid & 255;
        int inst = ((bid - 80) << 2) | sub;
        const float* Cg = (inst < 64) ? ws + OFF_CLN + (size_t)inst * 5000
                                      : ws + OFF_CGN + (size_t)(inst - 64) * 5000;
        float* outp = (inst < 64) ? ws + OFF_OTLN + inst : ws + OFF_OTGN + (inst - 64);
        float* S = smem + (sub << 8);
        float* gS = S;          // [104]
        float* fS = S + 104;    // [52]
        bool actf = stid < 100; int rf = stid >> 1, hf = stid & 1;
        bool actg = (stid >= 128) && (stid < 228); int cg = stid - 128;
        float Creg[52];
        if (actf) {
            #pragma unroll
            for (int k = 0; k < 52; ++k) {
                int cc = hf * 52 + k;
                Creg[k] = (cc < 100) ? Cg[(size_t)rf * 100 + cc] : 3.0e30f;
            }
        } else if (actg) {
            #pragma unroll
            for (int k = 0; k < 52; ++k)
                Creg[k] = (k < 50) ? Cg[(size_t)k * 100 + cg] : 3.0e30f;
        }
        if (stid < 104) gS[stid] = (stid < 100) ? 8.0f * LC100 : -1.0e30f;
        if (stid == 0) { fS[50] = -1.0e30f; fS[51] = -1.0e30f; }
        __syncthreads();
        float fr = 0.f, gr = 0.f;
        for (int it = 0; it < NITER; ++it) {
            float eps = eps_at(it), ie2 = (1.0f / eps) * LOG2E;
            if (actf) {
                const float4* g4 = (const float4*)(gS + hf * 52);
                float m0=-3.4e38f, m1=-3.4e38f, m2=-3.4e38f, m3=-3.4e38f;
                #pragma unroll
                for (int k = 0; k < 13; ++k) {
                    float4 gv = g4[k];
                    m0 = fmaxf(m0, gv.x - Creg[4*k+0]);
                    m1 = fmaxf(m1, gv.y - Creg[4*k+1]);
                    m2 = fmaxf(m2, gv.z - Creg[4*k+2]);
                    m3 = fmaxf(m3, gv.w - Creg[4*k+3]);
                }
                float m = fmaxf(fmaxf(m0, m1), fmaxf(m2, m3));
                m = fmaxf(m, __shfl_xor(m, 1));
                float s0=0.f, s1=0.f, s2=0.f, s3=0.f;
                #pragma unroll
                for (int k = 0; k < 13; ++k) {
                    float4 gv = g4[k];
                    s0 += exp2f((gv.x - Creg[4*k+0] - m) * ie2);
                    s1 += exp2f((gv.y - Creg[4*k+1] - m) * ie2);
                    s2 += exp2f((gv.z - Creg[4*k+2] - m) * ie2);
                    s3 += exp2f((gv.w - Creg[4*k+3] - m) * ie2);
                }
                float s = (s0 + s1) + (s2 + s3);
                s += __shfl_xor(s, 1);
                fr = -fmaf(eps * LN2, __log2f(s), m);
                if (hf == 0) fS[rf] = fmaf(eps, LC50, fr);
            }
            __syncthreads();
            if (actg) {
                const float4* f4 = (const float4*)fS;
                float m0=-3.4e38f, m1=-3.4e38f, m2=-3.4e38f, m3=-3.4e38f;
                #pragma unroll
                for (int k = 0; k < 13; ++k) {
                    float4 fv = f4[k];
                    m0 = fmaxf(m0, fv.x - Creg[4*k+0]);
                    m1 = fmaxf(m1, fv.y - Creg[4*k+1]);
                    m2 = fmaxf(m2, fv.z - Creg[4*k+2]);
                    m3 = fmaxf(m3, fv.w - Creg[4*k+3]);
                }
                float m = fmaxf(fmaxf(m0, m1), fmaxf(m2, m3));
                float s0=0.f, s1=0.f, s2=0.f, s3=0.f;
                #pragma unroll
                for (int k = 0; k < 13; ++k) {
                    float4 fv = f4[k];
                    s0 += exp2f((fv.x - Creg[4*k+0] - m) * ie2);
                    s1 += exp2f((fv.y - Creg[4*k+1] - m) * ie2);
                    s2 += exp2f((fv.z - Creg[4*k+2] - m) * ie2);
                    s3 += exp2f((fv.w - Creg[4*k+3] - m) * ie2);
                }
                gr = -fmaf(eps * LN2, __log2f((s0+s1)+(s2+s3)), m);
                float epsn = eps_at(it + 1);
                gS[cg] = fmaf(epsn, LC100, gr);
            }
            __syncthreads();
        }
        float contrib = 0.f;
        if (actf && hf == 0) contrib += 0.02f * fr;
        if (actg) contrib += 0.01f * gr;
        #pragma unroll
        for (int off = 1; off < 64; off <<= 1) contrib += __shfl_xor(contrib, off);
        if ((tid & 63) == 0) smem[1024 + (tid >> 6)] = contrib;
        __syncthreads();
        if (stid == 0) {
            int b4 = 1024 + (sub << 2);
            *outp = smem[b4] + smem[b4+1] + smem[b4+2] + smem[b4+3];
        }

    } else if (bid < 115) {
        // ---- tt x4 (50x50 sym): full column in regs ----
        int sub = tid >> 8, stid = tid & 255;
        int inst = ((bid - 112) << 2) | sub;
        bool live = inst < 10;
        const float* Cg = ws + OFF_CTT + (size_t)inst * 2500;
        float* S = smem + (sub << 8);
        bool act = live && (stid < 50);
        float Creg[52];
        if (act) {
            #pragma unroll
            for (int k = 0; k < 52; ++k)
                Creg[k] = (k < 50) ? Cg[(size_t)k * 50 + stid] : 3.0e30f;
        }
        if (live && stid < 50) S[stid] = 8.0f * LC50;
        if (live && stid >= 50 && stid < 52) { S[stid] = -1.0e30f; S[52 + stid] = -1.0e30f; }
        __syncthreads();
        float h = 0.f, fs = 0.f;
        for (int app = 0; app < 54; ++app) {
            float eps = eps_at(app >> 1);
            if (act) {
                const float4* a4 = (const float4*)(S + (app & 1) * 52);
                float m0=-3.4e38f, m1=-3.4e38f, m2=-3.4e38f, m3=-3.4e38f;
                #pragma unroll
                for (int k = 0; k < 13; ++k) {
                    float4 av = a4[k];
                    m0 = fmaxf(m0, av.x - Creg[4*k+0]);
                    m1 = fmaxf(m1, av.y - Creg[4*k+1]);
                    m2 = fmaxf(m2, av.z - Creg[4*k+2]);
                    m3 = fmaxf(m3, av.w - Creg[4*k+3]);
                }
                float m = fmaxf(fmaxf(m0, m1), fmaxf(m2, m3));
                float ie2 = (1.0f / eps) * LOG2E;
                float s0=0.f, s1=0.f, s2=0.f, s3=0.f;
                #pragma unroll
                for (int k = 0; k < 13; ++k) {
                    float4 av = a4[k];
                    s0 += exp2f((av.x - Creg[4*k+0] - m) * ie2);
                    s1 += exp2f((av.y - Creg[4*k+1] - m) * ie2);
                    s2 += exp2f((av.z - Creg[4*k+2] - m) * ie2);
                    s3 += exp2f((av.w - Creg[4*k+3] - m) * ie2);
                }
                h = -fmaf(eps * LN2, __log2f((s0+s1)+(s2+s3)), m);
                if (app == 52) fs = h;
                float epsn = eps_at((app + 1) >> 1);
                S[((app + 1) & 1) * 52 + stid] = fmaf(epsn, LC50, h);
            }
            __syncthreads();
        }
        float contrib = act ? 0.02f * (fs + h) : 0.f;
        #pragma unroll
        for (int off = 1; off < 64; off <<= 1) contrib += __shfl_xor(contrib, off);
        if ((tid & 63) == 0) smem[1024 + (tid >> 6)] = contrib;
        __syncthreads();
        if (stid == 0 && live) {
            int b4 = 1024 + (sub << 2);
            ws[OFF_OTTT + inst] = smem[b4] + smem[b4+1] + smem[b4+2] + smem[b4+3];
        }

    } else {
        // ---- cross x2 (256x50): 512 thr/inst, 256 active; f-update: gSp via shfl
        //      broadcast (1 ds_read/iter), CsT columns per-lane (unavoidable). ----
        int sub = tid >> 9, stid = tid & 511;
        int inst = ((bid - 115) << 1) | sub;
        int i = inst / 10, c = inst - i * 10;
        float* base = smem + sub * 13324;
        float* CsT = base;                 // [50][260]
        float* agS = base + 13000;         // [256] = eps*la + f
        float* gSp = base + 13260;         // [52] (+pad up to 13324)
        float* red = smem + 26648;         // [16]
        const float* Cgbase = ws + OFF_CX + (size_t)i * (500 * 256) + (size_t)c * (50 * 256);
        bool wk = stid < 256;
        if (wk) {
            for (int e = stid; e < 3200; e += 256) {
                int r = e >> 6, n4 = (e & 63) << 2;
                *(float4*)&CsT[r * 260 + n4] = *(const float4*)&Cgbase[(size_t)e << 2];
            }
        }
        float w = 0.f, la_r = 0.f;
        if (wk) {
            w = weight[(size_t)i * LA + stid];
            la_r = (w > 0.f) ? __logf(fmaxf(w, 1e-30f)) : -1e9f;
            if (stid < 52) gSp[stid] = (stid < 50) ? 0.f : -1.0e30f;
        }
        __syncthreads();
        int grp = stid >> 4, j = stid & 15;
        for (int it = 0; it < NITER; ++it) {
            float eps = eps_at(it), ie2 = (1.0f / eps) * LOG2E;
            if (wk) {
                float gv = gSp[stid & 63];   // lanes 0..49 carry gSp[0..49] per wave
                float m0=-3.4e38f, m1=-3.4e38f, m2=-3.4e38f, m3=-3.4e38f;
                #pragma unroll
                for (int r = 0; r < 48; r += 4) {
                    m0 = fmaxf(m0, __shfl(gv, r+0) - CsT[(r+0)*260 + stid]);
                    m1 = fmaxf(m1, __shfl(gv, r+1) - CsT[(r+1)*260 + stid]);
                    m2 = fmaxf(m2, __shfl(gv, r+2) - CsT[(r+2)*260 + stid]);
                    m3 = fmaxf(m3, __shfl(gv, r+3) - CsT[(r+3)*260 + stid]);
                }
                m0 = fmaxf(m0, __shfl(gv, 48) - CsT[48*260 + stid]);
                m1 = fmaxf(m1, __shfl(gv, 49) - CsT[49*260 + stid]);
                float m = fmaxf(fmaxf(m0, m1), fmaxf(m2, m3));
                float s0=0.f, s1=0.f, s2=0.f, s3=0.f;
                #pragma unroll
                for (int r = 0; r < 48; r += 4) {
                    s0 += exp2f((__shfl(gv, r+0) - CsT[(r+0)*260 + stid] - m) * ie2);
                    s1 += exp2f((__shfl(gv, r+1) - CsT[(r+1)*260 + stid] - m) * ie2);
                    s2 += exp2f((__shfl(gv, r+2) - CsT[(r+2)*260 + stid] - m) * ie2);
                    s3 += exp2f((__shfl(gv, r+3) - CsT[(r+3)*260 + stid] - m) * ie2);
                }
                s0 += exp2f((__shfl(gv, 48) - CsT[48*260 + stid] - m) * ie2);
                s1 += exp2f((__shfl(gv, 49) - CsT[49*260 + stid] - m) * ie2);
                float L = fmaf(eps * LN2, __log2f((s0+s1)+(s2+s3)), m);
                float f = -fmaf(eps, LC50, L);
                agS[stid] = fmaf(eps, la_r, f);
            }
            __syncthreads();
            if (wk) {
                float4 agr[4];
                #pragma unroll
                for (int q = 0; q < 4; ++q)
                    agr[q] = *(const float4*)&agS[(j << 2) + (q << 6)];
                for (int o = grp; o < 50; o += 16) {
                    const float* Cr = &CsT[o * 260];
                    float u[16];
                    #pragma unroll
                    for (int q = 0; q < 4; ++q) {
                        float4 cv = *(const float4*)&Cr[(j << 2) + (q << 6)];
                        u[4*q+0] = agr[q].x - cv.x;
                        u[4*q+1] = agr[q].y - cv.y;
                        u[4*q+2] = agr[q].z - cv.z;
                        u[4*q+3] = agr[q].w - cv.w;
                    }
                    float a0 = fmaxf(fmaxf(u[0], u[4]),  fmaxf(u[8],  u[12]));
                    float a1 = fmaxf(fmaxf(u[1], u[5]),  fmaxf(u[9],  u[13]));
                    float a2 = fmaxf(fmaxf(u[2], u[6]),  fmaxf(u[10], u[14]));
                    float a3 = fmaxf(fmaxf(u[3], u[7]),  fmaxf(u[11], u[15]));
                    float m = fmaxf(fmaxf(a0, a1), fmaxf(a2, a3));
                    #pragma unroll
                    for (int off = 1; off < 16; off <<= 1) m = fmaxf(m, __shfl_xor(m, off));
                    float s0=0.f, s1=0.f, s2=0.f, s3=0.f;
                    #pragma unroll
                    for (int k = 0; k < 16; ++k) {
                        float e = exp2f((u[k] - m) * ie2);
                        if ((k & 3) == 0) s0 += e;
                        else if ((k & 3) == 1) s1 += e;
                        else if ((k & 3) == 2) s2 += e;
                        else s3 += e;
                    }
                    float s = (s0 + s1) + (s2 + s3);
                    #pragma unroll
                    for (int off = 1; off < 16; off <<= 1) s += __shfl_xor(s, off);
                    if (j == 0) gSp[o] = -fmaf(eps * LN2, __log2f(s), m);
                }
            }
            __syncthreads();
        }
        float contrib = 0.f;
        if (wk) {
            float f_t = agS[stid] - 0.0025f * la_r;
            contrib = w * f_t + (stid < 50 ? 0.02f * gSp[stid] : 0.f);
        }
        #pragma unroll
        for (int off = 1; off < 64; off <<= 1) contrib += __shfl_xor(contrib, off);
        if ((tid & 63) == 0) red[tid >> 6] = contrib;
        __syncthreads();
        if (stid == 0) {
            int b8 = sub << 3;
            float s = 0.f;
            #pragma unroll
            for (int k = 0; k < 4; ++k) s += red[b8 + k];
            ws[OFF_OTX + inst] = s;
        }
    }
}

// ---------------- K3: final loss assembly ----------------
__global__ void assemble_kernel(const int* __restrict__ grade, const int* __restrict__ gneg,
                                const float* __restrict__ ws, float* __restrict__ out) {
    int i = threadIdx.x;
    float total = 0.f;
    if (i < 64) {
        float aa  = ws[OFF_OTAA + i];
        float nn  = ws[OFF_OTNN + i];
        float lnv = ws[OFF_OTLN + i];
        float gnv = ws[OFF_OTGN + i];
        int g  = grade[i];
        int gi = gneg[i];
        float tt9 = ws[OFF_OTTT + 9];
        float ttg = ws[OFF_OTTT + gi];
        float Slast = lnv - 0.5f * tt9 - 0.5f * nn;
        float Sgn   = gnv - 0.5f * ttg - 0.5f * nn;
        float Sv[10];
        #pragma unroll
        for (int k = 0; k < 10; k++)
            Sv[k] = ws[OFF_OTX + i * 10 + k] - 0.5f * aa - 0.5f * ws[OFF_OTTT + k];
        float pos = 0.f;
        #pragma unroll
        for (int k = 0; k < 10; k++) pos = (k == g) ? Sv[k] : pos;
        float hc = 0.f;
        #pragma unroll
        for (int k = 0; k < 10; k++)
            if (k != g) hc += fmaxf(pos - Sv[k] + MARGIN, 0.f);
        float hn = fmaxf(pos - Slast + MARGIN, 0.f);
        total = hc + hn + fabsf(Sgn - Slast);
    }
    #pragma unroll
    for (int off = 1; off < 64; off <<= 1) total += __shfl_xor(total, off);
    if (i == 0) out[0] = total * (1.0f / 64.0f);
}

extern "C" void kernel_launch(void* const* d_in, const int* in_sizes, int n_in,
                              void* d_out, int out_size, void* d_ws, size_t ws_size,
                              hipStream_t stream) {
    const float* anchor = (const float*)d_in[0];
    const int*   grade  = (const int*)d_in[2];
    const float* weight = (const float*)d_in[3];
    const float* neg    = (const float*)d_in[4];
    const int*   gneg   = (const int*)d_in[5];
    const float* t0     = (const float*)d_in[6];
    float* ws  = (float*)d_ws;
    float* out = (float*)d_out;

    sq_kernel      <<<5821, 256, 0, stream>>>(anchor, neg, t0, ws);
    cost128        <<<970, 256, 0, stream>>>(anchor, neg, t0, gneg, ws);
    sink_fused     <<<435, 1024, 0, stream>>>(weight, ws);
    assemble_kernel<<<1, 64, 0, stream>>>(grade, gneg, ws, out);
}

// Round 19
// 590.938 us; speedup vs baseline: 1.0356x; 1.0356x over previous
//
#include <hip/hip_runtime.h>

// Problem constants
#define NB   64
#define LA   256
#define DD   512
#define NCLS 10
#define NREF 50
#define NNEG 100
#define MARGIN 10.0f
#define NITER 27

#define LOG2E 1.44269504f
#define LN2   0.69314718f
#define LC50  (-3.9120230054f)   // log(1/50)
#define LC100 (-4.6051701860f)   // log(1/100)

// ---- workspace layout (float offsets) ----
// cross cost stored TRANSPOSED: [b][500][256] (t0-point major)
#define OFF_CX   ((size_t)0)
#define SZ_CX    ((size_t)64*500*256)
#define OFF_CAA  (OFF_CX + SZ_CX)
#define SZ_CAA   ((size_t)64*256*256)
#define OFF_CNN  (OFF_CAA + SZ_CAA)
#define SZ_CNN   ((size_t)64*100*100)
#define OFF_CLN  (OFF_CNN + SZ_CNN)
#define SZ_CLN   ((size_t)64*50*100)
#define OFF_CGN  (OFF_CLN + SZ_CLN)
#define SZ_CGN   ((size_t)64*50*100)
#define OFF_CTT  (OFF_CGN + SZ_CGN)
#define SZ_CTT   ((size_t)10*50*50)
#define OFF_SQA  (OFF_CTT + SZ_CTT)
#define OFF_SQN  (OFF_SQA + (size_t)64*256)
#define OFF_SQT  (OFF_SQN + (size_t)64*100)
#define OFF_OTX  (OFF_SQT + (size_t)500)
#define OFF_OTAA (OFF_OTX + (size_t)640)
#define OFF_OTNN (OFF_OTAA + (size_t)64)
#define OFF_OTLN (OFF_OTNN + (size_t)64)
#define OFF_OTGN (OFF_OTLN + (size_t)64)
#define OFF_OTTT (OFF_OTGN + (size_t)64)

__device__ __forceinline__ float eps_at(int it) {
    return (it < 12) ? ldexpf(8.0f, -it) : 0.0025f;
}

// ---------------- K0: 0.5 * squared norms ----------------
__global__ __launch_bounds__(256) void sq_kernel(const float* __restrict__ anchor,
                                                 const float* __restrict__ neg,
                                                 const float* __restrict__ t0,
                                                 float* __restrict__ ws) {
    int gw   = (blockIdx.x * 256 + threadIdx.x) >> 6;
    int lane = threadIdx.x & 63;
    const int nA = NB * LA, nN = NB * NNEG, nT = NCLS * NREF;
    if (gw >= nA + nN + nT) return;
    const float* row; float* outp;
    if (gw < nA)           { row = anchor + (size_t)gw * DD;          outp = ws + OFF_SQA + gw; }
    else if (gw < nA + nN) { int r = gw - nA;      row = neg + (size_t)r * DD; outp = ws + OFF_SQN + r; }
    else                   { int r = gw - nA - nN; row = t0  + (size_t)r * DD; outp = ws + OFF_SQT + r; }
    const float4* r4 = (const float4*)row;
    float4 u = r4[lane * 2], v = r4[lane * 2 + 1];
    float s = u.x*u.x + u.y*u.y + u.z*u.z + u.w*u.w
            + v.x*v.x + v.y*v.y + v.z*v.z + v.w*v.w;
    #pragma unroll
    for (int off = 1; off < 64; off <<= 1) s += __shfl_xor(s, off);
    if (lane == 0) *outp = 0.5f * s;
}

// ---------------- K1: cost matrices — 128x128 tile, 8x8 micro, K=16 ----------------
#define CTM 128
#define CTK 16
__global__ __launch_bounds__(256) void cost128(const float* __restrict__ anchor,
                                               const float* __restrict__ neg,
                                               const float* __restrict__ t0,
                                               const int* __restrict__ gneg,
                                               float* __restrict__ ws) {
    __shared__ __align__(16) float As[CTK][CTM];
    __shared__ __align__(16) float Bs[CTK][CTM];
    int bid = blockIdx.x, tid = threadIdx.x;
    const float *X, *Y, *sqx, *sqy;
    float* Cout; int N, M, ldc, r0, c0;
    bool tr = false;
    if (bid < 512) {
        int b = bid >> 3, t = bid & 7;
        r0 = (t >> 2) * 128; c0 = (t & 3) * 128;
        X = anchor + (size_t)b * LA * DD; Y = t0; N = LA; M = 500; ldc = 500;
        Cout = ws + OFF_CX + (size_t)b * 500 * 256;
        sqx = ws + OFF_SQA + b * LA; sqy = ws + OFF_SQT;
        tr = true;
    } else if (bid < 768) {
        int b2 = bid - 512; int b = b2 >> 2, t = b2 & 3;
        r0 = (t >> 1) * 128; c0 = (t & 1) * 128;
        X = Y = anchor + (size_t)b * LA * DD; N = M = LA; ldc = LA;
        Cout = ws + OFF_CAA + (size_t)b * LA * LA;
        sqx = sqy = ws + OFF_SQA + b * LA;
    } else if (bid < 832) {
        int b = bid - 768; r0 = 0; c0 = 0;
        X = Y = neg + (size_t)b * NNEG * DD; N = M = NNEG; ldc = NNEG;
        Cout = ws + OFF_CNN + (size_t)b * NNEG * NNEG;
        sqx = sqy = ws + OFF_SQN + b * NNEG;
    } else if (bid < 896) {
        int b = bid - 832; r0 = 0; c0 = 0;
        X = t0 + (size_t)9 * NREF * DD; Y = neg + (size_t)b * NNEG * DD;
        N = NREF; M = NNEG; ldc = NNEG;
        Cout = ws + OFF_CLN + (size_t)b * NREF * NNEG;
        sqx = ws + OFF_SQT + 9 * NREF; sqy = ws + OFF_SQN + b * NNEG;
    } else if (bid < 960) {
        int b = bid - 896; r0 = 0; c0 = 0;
        int gc = gneg[b];
        X = t0 + (size_t)gc * NREF * DD; Y = neg + (size_t)b * NNEG * DD;
        N = NREF; M = NNEG; ldc = NNEG;
        Cout = ws + OFF_CGN + (size_t)b * NREF * NNEG;
        sqx = ws + OFF_SQT + gc * NREF; sqy = ws + OFF_SQN + b * NNEG;
    } else {
        int c = bid - 960; r0 = 0; c0 = 0;
        X = Y = t0 + (size_t)c * NREF * DD; N = M = NREF; ldc = NREF;
        Cout = ws + OFF_CTT + (size_t)c * NREF * NREF;
        sqx = sqy = ws + OFF_SQT + c * NREF;
    }
    int row = tid & 127, kq = tid >> 7;
    int tx = tid & 15, ty = tid >> 4;
    bool xok = (r0 + row) < N, yok = (c0 + row) < M;
    const float* xrow = X + (size_t)(r0 + row) * DD + kq * 8;
    const float* yrow = Y + (size_t)(c0 + row) * DD + kq * 8;
    float acc[8][8];
    #pragma unroll
    for (int a = 0; a < 8; a++)
        #pragma unroll
        for (int b = 0; b < 8; b++) acc[a][b] = 0.f;
    for (int k0 = 0; k0 < DD; k0 += CTK) {
        float4 xa0 = xok ? *(const float4*)(xrow + k0)     : make_float4(0,0,0,0);
        float4 xa1 = xok ? *(const float4*)(xrow + k0 + 4) : make_float4(0,0,0,0);
        float4 ya0 = yok ? *(const float4*)(yrow + k0)     : make_float4(0,0,0,0);
        float4 ya1 = yok ? *(const float4*)(yrow + k0 + 4) : make_float4(0,0,0,0);
        __syncthreads();
        int kb = kq * 8;
        As[kb+0][row]=xa0.x; As[kb+1][row]=xa0.y; As[kb+2][row]=xa0.z; As[kb+3][row]=xa0.w;
        As[kb+4][row]=xa1.x; As[kb+5][row]=xa1.y; As[kb+6][row]=xa1.z; As[kb+7][row]=xa1.w;
        Bs[kb+0][row]=ya0.x; Bs[kb+1][row]=ya0.y; Bs[kb+2][row]=ya0.z; Bs[kb+3][row]=ya0.w;
        Bs[kb+4][row]=ya1.x; Bs[kb+5][row]=ya1.y; Bs[kb+6][row]=ya1.z; Bs[kb+7][row]=ya1.w;
        __syncthreads();
        #pragma unroll
        for (int k = 0; k < CTK; k++) {
            float4 a0 = *(const float4*)&As[k][ty << 3];
            float4 a1 = *(const float4*)&As[k][(ty << 3) + 4];
            float4 b0 = *(const float4*)&Bs[k][tx << 3];
            float4 b1 = *(const float4*)&Bs[k][(tx << 3) + 4];
            float av[8] = {a0.x,a0.y,a0.z,a0.w,a1.x,a1.y,a1.z,a1.w};
            float bv[8] = {b0.x,b0.y,b0.z,b0.w,b1.x,b1.y,b1.z,b1.w};
            #pragma unroll
            for (int a = 0; a < 8; a++)
                #pragma unroll
                for (int b = 0; b < 8; b++)
                    acc[a][b] = fmaf(av[a], bv[b], acc[a][b]);
        }
    }
    #pragma unroll
    for (int a = 0; a < 8; a++) {
        int n = r0 + (ty << 3) + a;
        if (n < N) {
            float sx = sqx[n];
            #pragma unroll
            for (int b = 0; b < 8; b++) {
                int m = c0 + (tx << 3) + b;
                if (m < M) {
                    float v = sx + sqy[m] - acc[a][b];
                    if (tr) Cout[(size_t)m * 256 + n] = v;
                    else    Cout[(size_t)n * ldc + m] = v;
                }
            }
        }
    }
}

// ---------------- K2: ALL sinkhorn in one launch ----------------
// 435 blocks x 1024 thr. bid<64 aa; 64..79 nn x4; 80..111 ln/gn x4; 112..114 tt x4;
// 115..434 cross x2 (512 thr each, 256 active). LDS 106.6 KB -> 1 block/CU.
__global__ __launch_bounds__(1024) void sink_fused(const float* __restrict__ weight,
                                                   float* __restrict__ ws) {
    __shared__ __align__(16) float smem[26664];
    int bid = blockIdx.x, tid = threadIdx.x;

    if (bid < 64) {
        // ---- aa: padded ah [2][4][68], wave-local reduce, 1 barrier/app ----
        float* ahp = smem;
        float* red = smem + 1024;
        int w = tid >> 6, lane = tid & 63;
        int c = (w << 4) | (lane & 15);
        int rg = lane >> 4;
        const float* Cg = ws + OFF_CAA + ((size_t)bid << 16);
        float Creg[64];
        #pragma unroll
        for (int k = 0; k < 64; ++k)
            Creg[k] = Cg[(size_t)((rg << 6) + k) * 256 + c];
        float wgt = weight[(size_t)bid * LA + c];
        float la = (wgt > 0.f) ? __logf(fmaxf(wgt, 1e-30f)) : -1e9f;
        float h = 0.f, fs = 0.f;
        int wseg = (c >> 6) * 68 + (c & 63);
        if (rg == 0) ahp[wseg] = 8.0f * la;
        __syncthreads();
        for (int app = 0; app < 54; ++app) {
            float eps = eps_at(app >> 1);
            const float4* a4 = (const float4*)(ahp + (app & 1) * 272 + rg * 68);
            float m0=-3.4e38f, m1=-3.4e38f, m2=-3.4e38f, m3=-3.4e38f;
            #pragma unroll
            for (int k = 0; k < 16; ++k) {
                float4 av = a4[k];
                m0 = fmaxf(m0, av.x - Creg[4*k+0]);
                m1 = fmaxf(m1, av.y - Creg[4*k+1]);
                m2 = fmaxf(m2, av.z - Creg[4*k+2]);
                m3 = fmaxf(m3, av.w - Creg[4*k+3]);
            }
            float m = fmaxf(fmaxf(m0, m1), fmaxf(m2, m3));
            m = fmaxf(m, __shfl_xor(m, 16));
            m = fmaxf(m, __shfl_xor(m, 32));
            float ie2 = (1.0f / eps) * LOG2E;
            float s0=0.f, s1=0.f, s2=0.f, s3=0.f;
            #pragma unroll
            for (int k = 0; k < 16; ++k) {
                float4 av = a4[k];
                s0 += exp2f((av.x - Creg[4*k+0] - m) * ie2);
                s1 += exp2f((av.y - Creg[4*k+1] - m) * ie2);
                s2 += exp2f((av.z - Creg[4*k+2] - m) * ie2);
                s3 += exp2f((av.w - Creg[4*k+3] - m) * ie2);
            }
            float s = (s0 + s1) + (s2 + s3);
            s += __shfl_xor(s, 16);
            s += __shfl_xor(s, 32);
            h = -fmaf(eps * LN2, __log2f(s), m);
            if (app == 52) fs = h;
            float epsn = eps_at((app + 1) >> 1);
            if (rg == 0) ahp[((app + 1) & 1) * 272 + wseg] = fmaf(epsn, la, h);
            __syncthreads();
        }
        float contrib = (rg == 0) ? wgt * (fs + h) : 0.f;
        #pragma unroll
        for (int off = 1; off < 64; off <<= 1) contrib += __shfl_xor(contrib, off);
        if (lane == 0) red[w] = contrib;
        __syncthreads();
        if (tid == 0) {
            float s = 0.f;
            #pragma unroll
            for (int k = 0; k < 16; ++k) s += red[k];
            ws[OFF_OTAA + bid] = s;
        }

    } else if (bid < 80) {
        // ---- nn x4 (100x100 sym): lane-paired, Creg[52], 1 barrier/app ----
        int sub = tid >> 8, stid = tid & 255;
        int inst = ((bid - 64) << 2) | sub;
        const float* Cg = ws + OFF_CNN + (size_t)inst * 10000;
        float* S = smem + (sub << 8);
        bool act = stid < 200;
        int c = stid >> 1, rg = stid & 1;
        float Creg[52];
        if (act) {
            #pragma unroll
            for (int k = 0; k < 52; ++k) {
                int r = rg * 52 + k;
                Creg[k] = (r < 100) ? Cg[(size_t)r * 100 + c] : 3.0e30f;
            }
        }
        if (stid < 100) S[stid] = 8.0f * LC100;
        if (stid >= 100 && stid < 104) { S[stid] = -1.0e30f; S[104 + stid] = -1.0e30f; }
        __syncthreads();
        float h = 0.f, fs = 0.f;
        for (int app = 0; app < 54; ++app) {
            float eps = eps_at(app >> 1);
            if (act) {
                const float4* a4 = (const float4*)(S + (app & 1) * 104 + rg * 52);
                float m0=-3.4e38f, m1=-3.4e38f, m2=-3.4e38f, m3=-3.4e38f;
                #pragma unroll
                for (int k = 0; k < 13; ++k) {
                    float4 av = a4[k];
                    m0 = fmaxf(m0, av.x - Creg[4*k+0]);
                    m1 = fmaxf(m1, av.y - Creg[4*k+1]);
                    m2 = fmaxf(m2, av.z - Creg[4*k+2]);
                    m3 = fmaxf(m3, av.w - Creg[4*k+3]);
                }
                float m = fmaxf(fmaxf(m0, m1), fmaxf(m2, m3));
                m = fmaxf(m, __shfl_xor(m, 1));
                float ie2 = (1.0f / eps) * LOG2E;
                float s0=0.f, s1=0.f, s2=0.f, s3=0.f;
                #pragma unroll
                for (int k = 0; k < 13; ++k) {
                    float4 av = a4[k];
                    s0 += exp2f((av.x - Creg[4*k+0] - m) * ie2);
                    s1 += exp2f((av.y - Creg[4*k+1] - m) * ie2);
                    s2 += exp2f((av.z - Creg[4*k+2] - m) * ie2);
                    s3 += exp2f((av.w - Creg[4*k+3] - m) * ie2);
                }
                float s = (s0 + s1) + (s2 + s3);
                s += __shfl_xor(s, 1);
                h = -fmaf(eps * LN2, __log2f(s), m);
                if (app == 52) fs = h;
                float epsn = eps_at((app + 1) >> 1);
                if (rg == 0) S[((app + 1) & 1) * 104 + c] = fmaf(epsn, LC100, h);
            }
            __syncthreads();
        }
        float contrib = (act && rg == 0) ? 0.01f * (fs + h) : 0.f;
        #pragma unroll
        for (int off = 1; off < 64; off <<= 1) contrib += __shfl_xor(contrib, off);
        if ((tid & 63) == 0) smem[1024 + (tid >> 6)] = contrib;
        __syncthreads();
        if (stid == 0) {
            int b4 = 1024 + (sub << 2);
            ws[OFF_OTNN + inst] = smem[b4] + smem[b4+1] + smem[b4+2] + smem[b4+3];
        }

    } else if (bid < 112) {
        // ---- ln/gn x4 (50x100): f lane-paired, g thread-per-col ----
        int sub = tid >> 8, stid = tid & 255;
        int inst = ((bid - 80) << 2) | sub;
        const float* Cg = (inst < 64) ? ws + OFF_CLN + (size_t)inst * 5000
                                      : ws + OFF_CGN + (size_t)(inst - 64) * 5000;
        float* outp = (inst < 64) ? ws + OFF_OTLN + inst : ws + OFF_OTGN + (inst - 64);
        float* S = smem + (sub << 8);
        float* gS = S;          // [104]
        float* fS = S + 104;    // [52]
        bool actf = stid < 100; int rf = stid >> 1, hf = stid & 1;
        bool actg = (stid >= 128) && (stid < 228); int cg = stid - 128;
        float Creg[52];
        if (actf) {
            #pragma unroll
            for (int k = 0; k < 52; ++k) {
                int cc = hf * 52 + k;
                Creg[k] = (cc < 100) ? Cg[(size_t)rf * 100 + cc] : 3.0e30f;
            }
        } else if (actg) {
            #pragma unroll
            for (int k = 0; k < 52; ++k)
                Creg[k] = (k < 50) ? Cg[(size_t)k * 100 + cg] : 3.0e30f;
        }
        if (stid < 104) gS[stid] = (stid < 100) ? 8.0f * LC100 : -1.0e30f;
        if (stid == 0) { fS[50] = -1.0e30f; fS[51] = -1.0e30f; }
        __syncthreads();
        float fr = 0.f, gr = 0.f;
        for (int it = 0; it < NITER; ++it) {
            float eps = eps_at(it), ie2 = (1.0f / eps) * LOG2E;
            if (actf) {
                const float4* g4 = (const float4*)(gS + hf * 52);
                float m0=-3.4e38f, m1=-3.4e38f, m2=-3.4e38f, m3=-3.4e38f;
                #pragma unroll
                for (int k = 0; k < 13; ++k) {
                    float4 gv = g4[k];
                    m0 = fmaxf(m0, gv.x - Creg[4*k+0]);
                    m1 = fmaxf(m1, gv.y - Creg[4*k+1]);
                    m2 = fmaxf(m2, gv.z - Creg[4*k+2]);
                    m3 = fmaxf(m3, gv.w - Creg[4*k+3]);
                }
                float m = fmaxf(fmaxf(m0, m1), fmaxf(m2, m3));
                m = fmaxf(m, __shfl_xor(m, 1));
                float s0=0.f, s1=0.f, s2=0.f, s3=0.f;
                #pragma unroll
                for (int k = 0; k < 13; ++k) {
                    float4 gv = g4[k];
                    s0 += exp2f((gv.x - Creg[4*k+0] - m) * ie2);
                    s1 += exp2f((gv.y - Creg[4*k+1] - m) * ie2);
                    s2 += exp2f((gv.z - Creg[4*k+2] - m) * ie2);
                    s3 += exp2f((gv.w - Creg[4*k+3] - m) * ie2);
                }
                float s = (s0 + s1) + (s2 + s3);
                s += __shfl_xor(s, 1);
                fr = -fmaf(eps * LN2, __log2f(s), m);
                if (hf == 0) fS[rf] = fmaf(eps, LC50, fr);
            }
            __syncthreads();
            if (actg) {
                const float4* f4 = (const float4*)fS;
                float m0=-3.4e38f, m1=-3.4e38f, m2=-3.4e38f, m3=-3.4e38f;
                #pragma unroll
                for (int k = 0; k < 13; ++k) {
                    float4 fv = f4[k];
                    m0 = fmaxf(m0, fv.x - Creg[4*k+0]);
                    m1 = fmaxf(m1, fv.y - Creg[4*k+1]);
                    m2 = fmaxf(m2, fv.z - Creg[4*k+2]);
                    m3 = fmaxf(m3, fv.w - Creg[4*k+3]);
                }
                float m = fmaxf(fmaxf(m0, m1), fmaxf(m2, m3));
                float s0=0.f, s1=0.f, s2=0.f, s3=0.f;
                #pragma unroll
                for (int k = 0; k < 13; ++k) {
                    float4 fv = f4[k];
                    s0 += exp2f((fv.x - Creg[4*k+0] - m) * ie2);
                    s1 += exp2f((fv.y - Creg[4*k+1] - m) * ie2);
                    s2 += exp2f((fv.z - Creg[4*k+2] - m) * ie2);
                    s3 += exp2f((fv.w - Creg[4*k+3] - m) * ie2);
                }
                gr = -fmaf(eps * LN2, __log2f((s0+s1)+(s2+s3)), m);
                float epsn = eps_at(it + 1);
                gS[cg] = fmaf(epsn, LC100, gr);
            }
            __syncthreads();
        }
        float contrib = 0.f;
        if (actf && hf == 0) contrib += 0.02f * fr;
        if (actg) contrib += 0.01f * gr;
        #pragma unroll
        for (int off = 1; off < 64; off <<= 1) contrib += __shfl_xor(contrib, off);
        if ((tid & 63) == 0) smem[1024 + (tid >> 6)] = contrib;
        __syncthreads();
        if (stid == 0) {
            int b4 = 1024 + (sub << 2);
            *outp = smem[b4] + smem[b4+1] + smem[b4+2] + smem[b4+3];
        }

    } else if (bid < 115) {
        // ---- tt x4 (50x50 sym): full column in regs ----
        int sub = tid >> 8, stid = tid & 255;
        int inst = ((bid - 112) << 2) | sub;
        bool live = inst < 10;
        const float* Cg = ws + OFF_CTT + (size_t)inst * 2500;
        float* S = smem + (sub << 8);
        bool act = live && (stid < 50);
        float Creg[52];
        if (act) {
            #pragma unroll
            for (int k = 0; k < 52; ++k)
                Creg[k] = (k < 50) ? Cg[(size_t)k * 50 + stid] : 3.0e30f;
        }
        if (live && stid < 50) S[stid] = 8.0f * LC50;
        if (live && stid >= 50 && stid < 52) { S[stid] = -1.0e30f; S[52 + stid] = -1.0e30f; }
        __syncthreads();
        float h = 0.f, fs = 0.f;
        for (int app = 0; app < 54; ++app) {
            float eps = eps_at(app >> 1);
            if (act) {
                const float4* a4 = (const float4*)(S + (app & 1) * 52);
                float m0=-3.4e38f, m1=-3.4e38f, m2=-3.4e38f, m3=-3.4e38f;
                #pragma unroll
                for (int k = 0; k < 13; ++k) {
                    float4 av = a4[k];
                    m0 = fmaxf(m0, av.x - Creg[4*k+0]);
                    m1 = fmaxf(m1, av.y - Creg[4*k+1]);
                    m2 = fmaxf(m2, av.z - Creg[4*k+2]);
                    m3 = fmaxf(m3, av.w - Creg[4*k+3]);
                }
                float m = fmaxf(fmaxf(m0, m1), fmaxf(m2, m3));
                float ie2 = (1.0f / eps) * LOG2E;
                float s0=0.f, s1=0.f, s2=0.f, s3=0.f;
                #pragma unroll
                for (int k = 0; k < 13; ++k) {
                    float4 av = a4[k];
                    s0 += exp2f((av.x - Creg[4*k+0] - m) * ie2);
                    s1 += exp2f((av.y - Creg[4*k+1] - m) * ie2);
                    s2 += exp2f((av.z - Creg[4*k+2] - m) * ie2);
                    s3 += exp2f((av.w - Creg[4*k+3] - m) * ie2);
                }
                h = -fmaf(eps * LN2, __log2f((s0+s1)+(s2+s3)), m);
                if (app == 52) fs = h;
                float epsn = eps_at((app + 1) >> 1);
                S[((app + 1) & 1) * 52 + stid] = fmaf(epsn, LC50, h);
            }
            __syncthreads();
        }
        float contrib = act ? 0.02f * (fs + h) : 0.f;
        #pragma unroll
        for (int off = 1; off < 64; off <<= 1) contrib += __shfl_xor(contrib, off);
        if ((tid & 63) == 0) smem[1024 + (tid >> 6)] = contrib;
        __syncthreads();
        if (stid == 0 && live) {
            int b4 = 1024 + (sub << 2);
            ws[OFF_OTTT + inst] = smem[b4] + smem[b4+1] + smem[b4+2] + smem[b4+3];
        }

    } else {
        // ---- cross x2 (256x50): 512 thr/instance, 256 active ----
        int sub = tid >> 9, stid = tid & 511;
        int inst = ((bid - 115) << 1) | sub;
        int i = inst / 10, c = inst - i * 10;
        float* base = smem + sub * 13324;
        float* CsT = base;                 // [50][260]
        float* agS = base + 13000;         // [256] = eps*la + f
        float* gSp = base + 13260;         // [52]
        float* red = smem + 26648;         // [16]
        const float* Cgbase = ws + OFF_CX + (size_t)i * (500 * 256) + (size_t)c * (50 * 256);
        bool wk = stid < 256;
        if (wk) {
            for (int e = stid; e < 3200; e += 256) {
                int r = e >> 6, n4 = (e & 63) << 2;
                *(float4*)&CsT[r * 260 + n4] = *(const float4*)&Cgbase[(size_t)e << 2];
            }
        }
        float w = 0.f, la_r = 0.f;
        if (wk) {
            w = weight[(size_t)i * LA + stid];
            la_r = (w > 0.f) ? __logf(fmaxf(w, 1e-30f)) : -1e9f;
            if (stid < 52) gSp[stid] = (stid < 50) ? 0.f : -1.0e30f;
        }
        __syncthreads();
        float Creg[52];
        if (wk) {
            #pragma unroll
            for (int r = 0; r < 52; ++r) Creg[r] = (r < 50) ? CsT[r * 260 + stid] : 3.0e30f;
        }
        int grp = stid >> 4, j = stid & 15;
        for (int it = 0; it < NITER; ++it) {
            float eps = eps_at(it), ie2 = (1.0f / eps) * LOG2E;
            if (wk) {
                const float4* g4 = (const float4*)gSp;
                float m0=-3.4e38f, m1=-3.4e38f, m2=-3.4e38f, m3=-3.4e38f;
                #pragma unroll
                for (int k = 0; k < 13; ++k) {
                    float4 gv = g4[k];
                    m0 = fmaxf(m0, gv.x - Creg[4*k+0]);
                    m1 = fmaxf(m1, gv.y - Creg[4*k+1]);
                    m2 = fmaxf(m2, gv.z - Creg[4*k+2]);
                    m3 = fmaxf(m3, gv.w - Creg[4*k+3]);
                }
                float m = fmaxf(fmaxf(m0, m1), fmaxf(m2, m3));
                float s0=0.f, s1=0.f, s2=0.f, s3=0.f;
                #pragma unroll
                for (int k = 0; k < 13; ++k) {
                    float4 gv = g4[k];
                    s0 += exp2f((gv.x - Creg[4*k+0] - m) * ie2);
                    s1 += exp2f((gv.y - Creg[4*k+1] - m) * ie2);
                    s2 += exp2f((gv.z - Creg[4*k+2] - m) * ie2);
                    s3 += exp2f((gv.w - Creg[4*k+3] - m) * ie2);
                }
                float L = fmaf(eps * LN2, __log2f((s0+s1)+(s2+s3)), m);
                float f = -fmaf(eps, LC50, L);
                agS[stid] = fmaf(eps, la_r, f);
            }
            __syncthreads();
            if (wk) {
                float4 agr[4];
                #pragma unroll
                for (int q = 0; q < 4; ++q)
                    agr[q] = *(const float4*)&agS[(j << 2) + (q << 6)];
                for (int o = grp; o < 50; o += 16) {
                    const float* Cr = &CsT[o * 260];
                    float u[16];
                    #pragma unroll
                    for (int q = 0; q < 4; ++q) {
                        float4 cv = *(const float4*)&Cr[(j << 2) + (q << 6)];
                        u[4*q+0] = agr[q].x - cv.x;
                        u[4*q+1] = agr[q].y - cv.y;
                        u[4*q+2] = agr[q].z - cv.z;
                        u[4*q+3] = agr[q].w - cv.w;
                    }
                    float a0 = fmaxf(fmaxf(u[0], u[4]),  fmaxf(u[8],  u[12]));
                    float a1 = fmaxf(fmaxf(u[1], u[5]),  fmaxf(u[9],  u[13]));
                    float a2 = fmaxf(fmaxf(u[2], u[6]),  fmaxf(u[10], u[14]));
                    float a3 = fmaxf(fmaxf(u[3], u[7]),  fmaxf(u[11], u[15]));
                    float m = fmaxf(fmaxf(a0, a1), fmaxf(a2, a3));
                    #pragma unroll
                    for (int off = 1; off < 16; off <<= 1) m = fmaxf(m, __shfl_xor(m, off));
                    float s0=0.f, s1=0.f, s2=0.f, s3=0.f;
                    #pragma unroll
                    for (int k = 0; k < 16; ++k) {
                        float e = exp2f((u[k] - m) * ie2);
                        if ((k & 3) == 0) s0 += e;
                        else if ((k & 3) == 1) s1 += e;
                        else if ((k & 3) == 2) s2 += e;
                        else s3 += e;
                    }
                    float s = (s0 + s1) + (s2 + s3);
                    #pragma unroll
                    for (int off = 1; off < 16; off <<= 1) s += __shfl_xor(s, off);
                    if (j == 0) gSp[o] = -fmaf(eps * LN2, __log2f(s), m);
                }
            }
            __syncthreads();
        }
        float contrib = 0.f;
        if (wk) {
            float f_t = agS[stid] - 0.0025f * la_r;
            contrib = w * f_t + (stid < 50 ? 0.02f * gSp[stid] : 0.f);
        }
        #pragma unroll
        for (int off = 1; off < 64; off <<= 1) contrib += __shfl_xor(contrib, off);
        if ((tid & 63) == 0) red[tid >> 6] = contrib;
        __syncthreads();
        if (stid == 0) {
            int b8 = sub << 3;
            float s = 0.f;
            #pragma unroll
            for (int k = 0; k < 4; ++k) s += red[b8 + k];
            ws[OFF_OTX + inst] = s;
        }
    }
}

// ---------------- K3: final loss assembly ----------------
__global__ void assemble_kernel(const int* __restrict__ grade, const int* __restrict__ gneg,
                                const float* __restrict__ ws, float* __restrict__ out) {
    int i = threadIdx.x;
    float total = 0.f;
    if (i < 64) {
        float aa  = ws[OFF_OTAA + i];
        float nn  = ws[OFF_OTNN + i];
        float lnv = ws[OFF_OTLN + i];
        float gnv = ws[OFF_OTGN + i];
        int g  = grade[i];
        int gi = gneg[i];
        float tt9 = ws[OFF_OTTT + 9];
        float ttg = ws[OFF_OTTT + gi];
        float Slast = lnv - 0.5f * tt9 - 0.5f * nn;
        float Sgn   = gnv - 0.5f * ttg - 0.5f * nn;
        float Sv[10];
        #pragma unroll
        for (int k = 0; k < 10; k++)
            Sv[k] = ws[OFF_OTX + i * 10 + k] - 0.5f * aa - 0.5f * ws[OFF_OTTT + k];
        float pos = 0.f;
        #pragma unroll
        for (int k = 0; k < 10; k++) pos = (k == g) ? Sv[k] : pos;
        float hc = 0.f;
        #pragma unroll
        for (int k = 0; k < 10; k++)
            if (k != g) hc += fmaxf(pos - Sv[k] + MARGIN, 0.f);
        float hn = fmaxf(pos - Slast + MARGIN, 0.f);
        total = hc + hn + fabsf(Sgn - Slast);
    }
    #pragma unroll
    for (int off = 1; off < 64; off <<= 1) total += __shfl_xor(total, off);
    if (i == 0) out[0] = total * (1.0f / 64.0f);
}

extern "C" void kernel_launch(void* const* d_in, const int* in_sizes, int n_in,
                              void* d_out, int out_size, void* d_ws, size_t ws_size,
                              hipStream_t stream) {
    const float* anchor = (const float*)d_in[0];
    const int*   grade  = (const int*)d_in[2];
    const float* weight = (const float*)d_in[3];
    const float* neg    = (const float*)d_in[4];
    const int*   gneg   = (const int*)d_in[5];
    const float* t0     = (const float*)d_in[6];
    float* ws  = (float*)d_ws;
    float* out = (float*)d_out;

    sq_kernel      <<<5821, 256, 0, stream>>>(anchor, neg, t0, ws);
    cost128        <<<970, 256, 0, stream>>>(anchor, neg, t0, gneg, ws);
    sink_fused     <<<435, 1024, 0, stream>>>(weight, ws);
    assemble_kernel<<<1, 64, 0, stream>>>(grade, gneg, ws, out);
}